// Round 2
// baseline (1100.758 us; speedup 1.0000x reference)
//
#include <hip/hip_runtime.h>
#include <hip/hip_bf16.h>

typedef __attribute__((ext_vector_type(8))) short short8_t;
typedef __attribute__((ext_vector_type(4))) float f32x4;

__device__ __forceinline__ float bf2f(unsigned short u) {
    return __uint_as_float(((unsigned)u) << 16);
}
__device__ __forceinline__ unsigned short f2bf(float f) {
    __hip_bfloat16 h = __float2bfloat16(f);
    return *reinterpret_cast<unsigned short*>(&h);
}

// window-order row r (r = wb*49 + n) -> natural token index
__device__ __forceinline__ int win_row_to_token(int r) {
    int wb = r / 49, n = r - wb * 49;
    int wq = wb & 7, hb = (wb >> 3) & 7, d = (wb >> 6) & 7, b = wb >> 9;
    int hh = n / 7, ww2 = n - hh * 7;
    return ((b * 8 + d) * 56 + hb * 7 + hh) * 56 + wq * 7 + ww2;
}

// ---------------- prep: scales, qkv bias, CPB-MLP -> rpb ----------------
__global__ __launch_bounds__(256) void prep_kernel(
    const float* __restrict__ logit_scale,
    const float* __restrict__ w1, const float* __restrict__ b1,
    const float* __restrict__ w2,
    const float* __restrict__ qb, const float* __restrict__ vb,
    const float* __restrict__ tabin, const int* __restrict__ rpi,
    float* __restrict__ scales, float* __restrict__ rpb,
    float* __restrict__ qkvb)
{
    int t = threadIdx.x;
    if (t < 8) {
        float v = logit_scale[t];
        scales[t] = expf(fminf(v, 4.6051702f)); // ln(100)
    }
    for (int i = t; i < 768; i += 256) {
        float o;
        if (i < 256) o = qb[i];
        else if (i < 512) o = 0.f;
        else o = vb[i - 512];
        qkvb[i] = o;
    }
    __shared__ float table[169][8];
    for (int i = t; i < 169; i += 256) {
        float c0 = tabin[i * 3], c1 = tabin[i * 3 + 1], c2 = tabin[i * 3 + 2];
        float acc[8] = {0.f, 0.f, 0.f, 0.f, 0.f, 0.f, 0.f, 0.f};
        for (int j = 0; j < 512; ++j) {
            float hv = c0 * w1[j * 3] + c1 * w1[j * 3 + 1] + c2 * w1[j * 3 + 2] + b1[j];
            hv = fmaxf(hv, 0.f);
            #pragma unroll
            for (int h = 0; h < 8; ++h) acc[h] += hv * w2[h * 512 + j];
        }
        #pragma unroll
        for (int h = 0; h < 8; ++h) table[i][h] = acc[h];
    }
    __syncthreads();
    for (int e = t; e < 2401; e += 256) {
        int idx = rpi[e];
        #pragma unroll
        for (int h = 0; h < 8; ++h) {
            float xv = table[idx][h];
            rpb[h * 2401 + e] = 16.f / (1.f + expf(-xv));
        }
    }
}

// ---------------- GEMM: C[M,N] = A[M,K] * W[N,K]^T + bias ----------------
// ACT: 0 none, 1 exact GELU.  SCATTER: output row window->natural token map.
// AF32: A operand is float32 (else bf16). W and bias always float32. C bf16.
template<int ACT, int SCATTER, int AF32>
__global__ __launch_bounds__(256) void gemm_kernel(
    const void* __restrict__ Av, const float* __restrict__ W,
    const float* __restrict__ bias, unsigned short* __restrict__ C,
    int M, int N, int K)
{
    constexpr int LDS_STRIDE = 72; // 64 + 8 pad elems; 144B rows
    __shared__ unsigned short As[128 * LDS_STRIDE];
    __shared__ unsigned short Bs[128 * LDS_STRIDE];
    const int tid = threadIdx.x;
    const int lane = tid & 63, wid = tid >> 6;
    const int wr = wid >> 1, wc = wid & 1;
    const int bm = blockIdx.x, bn = blockIdx.y;
    const size_t arow0 = (size_t)bm * 128;
    const size_t brow0 = (size_t)bn * 128;
    const int r16 = lane & 15, kq = (lane >> 4) * 8;
    f32x4 acc[4][4] = {};

    for (int kt = 0; kt < K; kt += 64) {
        if (AF32) {
            const float* A = (const float*)Av;
            #pragma unroll
            for (int i = 0; i < 8; ++i) {
                int s = tid + (i << 8);
                int row = s >> 4, c4 = (s & 15) << 2;
                float4 v = *reinterpret_cast<const float4*>(&A[(arow0 + row) * K + kt + c4]);
                short4 o;
                o.x = (short)f2bf(v.x); o.y = (short)f2bf(v.y);
                o.z = (short)f2bf(v.z); o.w = (short)f2bf(v.w);
                *reinterpret_cast<short4*>(&As[row * LDS_STRIDE + c4]) = o;
            }
        } else {
            const unsigned short* A = (const unsigned short*)Av;
            #pragma unroll
            for (int i = 0; i < 4; ++i) {
                int s = tid + (i << 8);
                int row = s >> 3, c8 = (s & 7) << 3;
                *reinterpret_cast<int4*>(&As[row * LDS_STRIDE + c8]) =
                    *reinterpret_cast<const int4*>(&A[(arow0 + row) * K + kt + c8]);
            }
        }
        #pragma unroll
        for (int i = 0; i < 8; ++i) {
            int s = tid + (i << 8);
            int row = s >> 4, c4 = (s & 15) << 2;
            float4 v = *reinterpret_cast<const float4*>(&W[(brow0 + row) * K + kt + c4]);
            short4 o;
            o.x = (short)f2bf(v.x); o.y = (short)f2bf(v.y);
            o.z = (short)f2bf(v.z); o.w = (short)f2bf(v.w);
            *reinterpret_cast<short4*>(&Bs[row * LDS_STRIDE + c4]) = o;
        }
        __syncthreads();
        #pragma unroll
        for (int kk = 0; kk < 2; ++kk) {
            short8_t af[4], bfr[4];
            #pragma unroll
            for (int m = 0; m < 4; ++m)
                af[m] = *reinterpret_cast<const short8_t*>(
                    &As[(wr * 64 + m * 16 + r16) * LDS_STRIDE + kk * 32 + kq]);
            #pragma unroll
            for (int n = 0; n < 4; ++n)
                bfr[n] = *reinterpret_cast<const short8_t*>(
                    &Bs[(wc * 64 + n * 16 + r16) * LDS_STRIDE + kk * 32 + kq]);
            #pragma unroll
            for (int m = 0; m < 4; ++m)
                #pragma unroll
                for (int n = 0; n < 4; ++n)
                    acc[m][n] = __builtin_amdgcn_mfma_f32_16x16x32_bf16(af[m], bfr[n], acc[m][n], 0, 0, 0);
        }
        __syncthreads();
    }

    const int rbase = (lane >> 4) * 4;
    #pragma unroll
    for (int n = 0; n < 4; ++n) {
        int gcol = bn * 128 + wc * 64 + n * 16 + r16;
        float bv = bias[gcol];
        #pragma unroll
        for (int m = 0; m < 4; ++m) {
            #pragma unroll
            for (int r = 0; r < 4; ++r) {
                int grow = bm * 128 + wr * 64 + m * 16 + rbase + r;
                float v = acc[m][n][r] + bv;
                if (ACT == 1) v = 0.5f * v * (1.f + erff(v * 0.70710678118f));
                size_t orow = SCATTER ? (size_t)win_row_to_token(grow) : (size_t)grow;
                C[orow * (size_t)N + gcol] = f2bf(v);
            }
        }
    }
}

// ---------------- attention: one block per (window, head) ----------------
__global__ __launch_bounds__(256) void attn_kernel(
    const unsigned short* __restrict__ qkv, const float* __restrict__ scales,
    const float* __restrict__ rpb, unsigned short* __restrict__ out)
{
    int blk = blockIdx.x;
    int h = blk & 7, wb = blk >> 3;
    int t = threadIdx.x;
    __shared__ float qn[49 * 32], kn[49 * 32], vv[49 * 32];
    __shared__ float S[49 * 50];
    __shared__ float invq[49], invk[49];
    __shared__ int toks[49];
    if (t < 49) toks[t] = win_row_to_token(wb * 49 + t);
    __syncthreads();

    for (int c = t; c < 392; c += 256) {
        int row = c >> 3, d0 = (c & 7) << 2;
        size_t base = (size_t)toks[row] * 768 + h * 32 + d0;
        short4 sq = *reinterpret_cast<const short4*>(&qkv[base]);
        short4 sk = *reinterpret_cast<const short4*>(&qkv[base + 256]);
        short4 sv = *reinterpret_cast<const short4*>(&qkv[base + 512]);
        int o = row * 32 + d0;
        qn[o + 0] = bf2f((unsigned short)sq.x); qn[o + 1] = bf2f((unsigned short)sq.y);
        qn[o + 2] = bf2f((unsigned short)sq.z); qn[o + 3] = bf2f((unsigned short)sq.w);
        kn[o + 0] = bf2f((unsigned short)sk.x); kn[o + 1] = bf2f((unsigned short)sk.y);
        kn[o + 2] = bf2f((unsigned short)sk.z); kn[o + 3] = bf2f((unsigned short)sk.w);
        vv[o + 0] = bf2f((unsigned short)sv.x); vv[o + 1] = bf2f((unsigned short)sv.y);
        vv[o + 2] = bf2f((unsigned short)sv.z); vv[o + 3] = bf2f((unsigned short)sv.w);
    }
    __syncthreads();

    if (t < 98) {
        int which = (t >= 49) ? 1 : 0;
        int row = which ? t - 49 : t;
        const float* src = which ? kn : qn;
        float s = 0.f;
        #pragma unroll
        for (int d = 0; d < 32; ++d) { float f = src[row * 32 + d]; s += f * f; }
        float inv = 1.f / fmaxf(sqrtf(s), 1e-12f);
        if (which) invk[row] = inv;
        else invq[row] = inv * scales[h]; // fold logit scale into q
    }
    __syncthreads();

    for (int e = t; e < 1568; e += 256) {
        int row = e >> 5;
        qn[e] *= invq[row];
        kn[e] *= invk[row];
    }
    __syncthreads();

    const float* rb = rpb + h * 2401;
    for (int e = t; e < 2401; e += 256) {
        int i = e / 49, j = e - i * 49;
        const float* qr = qn + i * 32;
        const float* kr = kn + j * 32;
        float s = 0.f;
        #pragma unroll
        for (int d = 0; d < 32; ++d) s += qr[d] * kr[d];
        S[i * 50 + j] = s + rb[e];
    }
    __syncthreads();

    if (t < 49) {
        float m = -1e30f;
        for (int j = 0; j < 49; ++j) m = fmaxf(m, S[t * 50 + j]);
        float sum = 0.f;
        for (int j = 0; j < 49; ++j) { float p = expf(S[t * 50 + j] - m); S[t * 50 + j] = p; sum += p; }
        float r = 1.f / sum;
        for (int j = 0; j < 49; ++j) S[t * 50 + j] *= r;
    }
    __syncthreads();

    for (int e = t; e < 1568; e += 256) {
        int i = e >> 5, d = e & 31;
        float s = 0.f;
        #pragma unroll
        for (int j = 0; j < 49; ++j) s += S[i * 50 + j] * vv[j * 32 + d];
        out[(size_t)(wb * 49 + i) * 256 + h * 32 + d] = f2bf(s);
    }
}

// ---------------- fused residual + LayerNorm (one wave per token) ----------------
// BASE_F32: residual base dtype. OUT_F32: output dtype. vin always bf16.
template<int BASE_F32, int OUT_F32>
__global__ __launch_bounds__(256) void ln_add_kernel(
    const void* __restrict__ basev, const unsigned short* __restrict__ vin,
    const float* __restrict__ gg, const float* __restrict__ bb,
    void* __restrict__ outv)
{
    int token = blockIdx.x * 4 + (threadIdx.x >> 6);
    int lane = threadIdx.x & 63;
    size_t off = (size_t)token * 256 + lane * 4;
    short4 raw = *reinterpret_cast<const short4*>(&vin[off]);
    float f0 = bf2f((unsigned short)raw.x), f1 = bf2f((unsigned short)raw.y);
    float f2 = bf2f((unsigned short)raw.z), f3 = bf2f((unsigned short)raw.w);
    float s  = f0 + f1 + f2 + f3;
    float s2 = f0 * f0 + f1 * f1 + f2 * f2 + f3 * f3;
    #pragma unroll
    for (int m = 32; m >= 1; m >>= 1) { s += __shfl_xor(s, m, 64); s2 += __shfl_xor(s2, m, 64); }
    float mu = s * 0.00390625f;
    float var = s2 * 0.00390625f - mu * mu;
    float inv = rsqrtf(var + 1e-5f);

    float b0, b1v, b2, b3;
    if (BASE_F32) {
        float4 braw = *reinterpret_cast<const float4*>(&((const float*)basev)[off]);
        b0 = braw.x; b1v = braw.y; b2 = braw.z; b3 = braw.w;
    } else {
        short4 braw = *reinterpret_cast<const short4*>(&((const unsigned short*)basev)[off]);
        b0 = bf2f((unsigned short)braw.x); b1v = bf2f((unsigned short)braw.y);
        b2 = bf2f((unsigned short)braw.z); b3 = bf2f((unsigned short)braw.w);
    }
    float4 graw = *reinterpret_cast<const float4*>(&gg[lane * 4]);
    float4 brw2 = *reinterpret_cast<const float4*>(&bb[lane * 4]);
    float o0 = b0 + (f0 - mu) * inv * graw.x + brw2.x;
    float o1 = b1v + (f1 - mu) * inv * graw.y + brw2.y;
    float o2 = b2 + (f2 - mu) * inv * graw.z + brw2.z;
    float o3 = b3 + (f3 - mu) * inv * graw.w + brw2.w;
    if (OUT_F32) {
        float4 o; o.x = o0; o.y = o1; o.z = o2; o.w = o3;
        *reinterpret_cast<float4*>(&((float*)outv)[off]) = o;
    } else {
        short4 o;
        o.x = (short)f2bf(o0); o.y = (short)f2bf(o1);
        o.z = (short)f2bf(o2); o.w = (short)f2bf(o3);
        *reinterpret_cast<short4*>(&((unsigned short*)outv)[off]) = o;
    }
}

extern "C" void kernel_launch(void* const* d_in, const int* in_sizes, int n_in,
                              void* d_out, int out_size, void* d_ws, size_t ws_size,
                              hipStream_t stream) {
    const float* x      = (const float*)d_in[0];
    const float* qkv_w  = (const float*)d_in[1];
    const float* q_bias = (const float*)d_in[2];
    const float* v_bias = (const float*)d_in[3];
    const float* lscale = (const float*)d_in[4];
    const float* cpb_w1 = (const float*)d_in[5];
    const float* cpb_b1 = (const float*)d_in[6];
    const float* cpb_w2 = (const float*)d_in[7];
    const float* proj_w = (const float*)d_in[8];
    const float* proj_b = (const float*)d_in[9];
    const float* n1g    = (const float*)d_in[10];
    const float* n1b    = (const float*)d_in[11];
    const float* fc1_w  = (const float*)d_in[12];
    const float* fc1_b  = (const float*)d_in[13];
    const float* fc2_w  = (const float*)d_in[14];
    const float* fc2_b  = (const float*)d_in[15];
    const float* n2g    = (const float*)d_in[16];
    const float* n2b    = (const float*)d_in[17];
    const float* rct    = (const float*)d_in[18];
    const int*   rpi    = (const int*)d_in[19];

    char* ws = (char*)d_ws;
    // region 0 [0, 205520896): qkv bf16 (154.1MB), later h bf16 (205.5MB)
    unsigned short* qkv    = (unsigned short*)(ws);
    unsigned short* hbuf   = (unsigned short*)(ws);
    // region 1 [205520896, 256901120): attn_o bf16 (window order), later x1 bf16
    unsigned short* attn_o = (unsigned short*)(ws + 205520896);
    unsigned short* x1     = (unsigned short*)(ws + 205520896);
    // region 2 [256901120, 308281344): projy bf16, later y bf16
    unsigned short* projy  = (unsigned short*)(ws + 256901120);
    float*          rpb    = (float*)(ws + 308281344);
    float*          scales = (float*)(ws + 308358176);
    float*          qkvb   = (float*)(ws + 308358208);

    const int M = 100352; // tokens

    prep_kernel<<<1, 256, 0, stream>>>(lscale, cpb_w1, cpb_b1, cpb_w2, q_bias, v_bias,
                                       rct, rpi, scales, rpb, qkvb);
    // qkv = x @ qkv_w^T + qkv_bias   (natural token order)
    gemm_kernel<0, 0, 1><<<dim3(784, 6), 256, 0, stream>>>(x, qkv_w, qkvb, qkv, M, 768, 256);
    // attention per (window, head) -> window-ordered (Bw*49, 256)
    attn_kernel<<<16384, 256, 0, stream>>>(qkv, scales, rpb, attn_o);
    // proj with row scatter back to natural order
    gemm_kernel<0, 1, 0><<<dim3(784, 2), 256, 0, stream>>>(attn_o, proj_w, proj_b, projy, M, 256, 256);
    // x1 = x + LN(proj_out)
    ln_add_kernel<1, 0><<<25088, 256, 0, stream>>>(x, projy, n1g, n1b, x1);
    // h = gelu(x1 @ fc1_w^T + fc1_b)
    gemm_kernel<1, 0, 0><<<dim3(784, 8), 256, 0, stream>>>(x1, fc1_w, fc1_b, hbuf, M, 1024, 256);
    // y = h @ fc2_w^T + fc2_b
    gemm_kernel<0, 0, 0><<<dim3(784, 2), 256, 0, stream>>>(hbuf, fc2_w, fc2_b, projy, M, 256, 1024);
    // out = x1 + LN(y)
    ln_add_kernel<0, 1><<<25088, 256, 0, stream>>>(x1, projy, n2g, n2b, d_out);
}